// Round 3
// baseline (1965.858 us; speedup 1.0000x reference)
//
#include <hip/hip_runtime.h>

// Problem constants
#define B_      64
#define CIN     32
#define H_      28
#define W_      28
#define K_      5
#define OH_     24
#define OW_     24
#define COUT    128
#define NPOS    (OH_ * OW_)          // 576
#define HW_     (H_ * W_)            // 784
#define XSTRIDE (CIN * HW_)          // 25088 floats per image
#define NPOSU   (B_ * NPOS)          // 36864 position units

// Main-kernel mapping
#define BLOCK    256
#define UBLOCKS  (NPOSU / BLOCK)     // 144
#define NTP      64                  // tree pairs total
#define TPB      4                   // tree pairs per block
#define TGROUPS  (NTP / TPB)         // 16
#define NXCD     8
#define UPX      (UBLOCKS / NXCD)    // 18 u-chunks per XCD

// Program layout (bytes). Per tree-pair: 6 groups of {6 L1-records + 1 L2-record}
// then 1 L3-record. L1 record = 48B gather offsets + 512B coeff pairs = 560B.
// L2/L3 record = 512B coeff pairs.
#define L1REC    560
#define L2REC    512
#define GRPSZ    (6 * L1REC + L2REC)     // 3872
#define PPSTRIDE (6 * GRPSZ + L2REC)     // 23744
#define L3OFF    (6 * GRPSZ)             // 23232
#define WS_NEEDED (NTP * PPSTRIDE)       // 1519616

__host__ __device__ constexpr int rec_off(int j3, int jr) {
    return j3 * GRPSZ + (jr < 6 ? jr * L1REC : 6 * L1REC);
}

typedef float f2 __attribute__((ext_vector_type(2)));
typedef float f4 __attribute__((ext_vector_type(4)));

// Guaranteed packed FMA: d = x*h + l on both halves.
__device__ __forceinline__ f2 pkfma(f2 x, f2 h, f2 l) {
    f2 d;
    asm("v_pk_fma_f32 %0, %1, %2, %3" : "=v"(d) : "v"(x), "v"(h), "v"(l));
    return d;
}

__device__ __forceinline__ f2 clamp2(f2 v) {
    f2 r;
    r.x = __builtin_amdgcn_fmed3f(v.x, 0.0f, 1.0f);
    r.y = __builtin_amdgcn_fmed3f(v.y, 0.0f, 1.0f);
    return r;
}

// Launder a (wave-uniform) pointer through VGPRs so coefficient loads become
// vector VMEM loads landing directly in VGPR pairs (not s_load + v_mov).
__device__ __forceinline__ const f4* opq(const void* p) {
    asm("" : "+v"(p));
    return (const f4*)p;
}

// One paired contraction: 64 interleaved coefficient pairs at cp, Horner nest
// over xs[0..5] (xs[5] innermost/LSB). Pure fma: leaf = c_lo + x5*c_hi.
__device__ __forceinline__ f2 contract_prog(const void* cptr, const f2 xs[6]) {
    const f4* cp = opq(cptr);
    f2 v[32];
#pragma unroll
    for (int k = 0; k < 32; ++k) {
        f4 c = cp[k];                      // {a.x,a.y,b.x,b.y}
        f2 lo; lo.x = c.x; lo.y = c.y;
        f2 hi; hi.x = c.z; hi.y = c.w;
        v[k] = pkfma(xs[5], hi, lo);
    }
#pragma unroll
    for (int k = 0; k < 16; ++k) v[k] = pkfma(xs[4], v[2*k+1], v[2*k]);
#pragma unroll
    for (int k = 0; k < 8; ++k)  v[k] = pkfma(xs[3], v[2*k+1], v[2*k]);
#pragma unroll
    for (int k = 0; k < 4; ++k)  v[k] = pkfma(xs[2], v[2*k+1], v[2*k]);
#pragma unroll
    for (int k = 0; k < 2; ++k)  v[k] = pkfma(xs[1], v[2*k+1], v[2*k]);
    return clamp2(pkfma(xs[0], v[1], v[0]));
}

__global__ __launch_bounds__(BLOCK, 4)
void lutconv_prog(const float* __restrict__ x,
                  const char* __restrict__ prog,
                  float* __restrict__ out) {
    // XCD-locality decode: all blocks of one u-chunk land on one XCD.
    const int bid = blockIdx.x;
    const int xcd = bid % NXCD;
    const int j   = bid / NXCD;          // 0..287
    const int tg  = j % TGROUPS;
    const int us  = j / TGROUPS;         // 0..17
    const int u   = xcd * UPX + us;      // 0..143

    const int g   = u * BLOCK + threadIdx.x;   // 0..36863
    const int b   = g / NPOS;
    const int pos = g - b * NPOS;
    const int oh  = pos / OW_;
    const int ow  = pos - oh * OW_;
    const int lin = oh * W_ + ow;

    const float* xb = x + (size_t)b * XSTRIDE;

#pragma unroll 1
    for (int tpi = 0; tpi < TPB; ++tpi) {
        const int tp = tg * TPB + tpi;         // tree pair -> channels 2tp, 2tp+1
        const char* pp = prog + (size_t)tp * PPSTRIDE;

        f2 h2[6];
#pragma unroll
        for (int j3 = 0; j3 < 6; ++j3) {
            f2 h1[6];
#pragma unroll
            for (int j1 = 0; j1 < 6; ++j1) {
                const char* rp = pp + rec_off(j3, j1);
                const int* oi = (const int*)rp;     // uniform -> s_load
                f2 xs[6];
#pragma unroll
                for (int jj = 0; jj < 6; ++jj) {
                    f2 w;
                    w.x = xb[oi[2*jj]   + lin];
                    w.y = xb[oi[2*jj+1] + lin];
                    xs[jj] = w;
                }
                h1[j1] = contract_prog(rp + 48, xs);
            }
            h2[j3] = contract_prog(pp + rec_off(j3, 6), h1);
        }
        f2 r = contract_prog(pp + L3OFF, h2);

        float* o = out + ((size_t)b * COUT + 2 * tp) * NPOS + pos;
        o[0]    = r.x;
        o[NPOS] = r.y;
    }
}

// ---- Program builder: one 64-thread block per (tree-pair, record) ----
// Resolves map3/map2 indirection, precomputes gather offsets, and converts
// each 64-entry LUT to multilinear coefficients (Mobius transform), storing
// tree-pair-interleaved coefficient pairs.
__global__ void prep_prog(const int* __restrict__ map1,
                          const float* __restrict__ lut1,
                          const int* __restrict__ map2,
                          const float* __restrict__ lut2,
                          const int* __restrict__ map3,
                          const float* __restrict__ lut3,
                          char* __restrict__ prog) {
    const int rec = blockIdx.x % 43;
    const int tp  = blockIdx.x / 43;
    const int lane = threadIdx.x;
    const int t0 = 2 * tp, t1 = 2 * tp + 1;

    const int j3 = rec / 7;
    const int jr = rec - 7 * j3;        // rec==42 -> j3==6

    char* rp;
    const float* lp0;
    const float* lp1;
    if (rec == 42) {                    // L3 root
        rp  = prog + (size_t)tp * PPSTRIDE + L3OFF;
        lp0 = lut3 + t0 * 64;
        lp1 = lut3 + t1 * 64;
    } else if (jr == 6) {               // L2 node for root input j3
        int n0 = map3[t0 * 6 + j3];
        int n1 = map3[t1 * 6 + j3];
        rp  = prog + (size_t)tp * PPSTRIDE + rec_off(j3, 6);
        lp0 = lut2 + (t0 * 6 + n0) * 64;
        lp1 = lut2 + (t1 * 6 + n1) * 64;
    } else {                            // L1 node: input jr of L2 node j3
        int n20 = map3[t0 * 6 + j3];
        int n21 = map3[t1 * 6 + j3];
        int n10 = map2[(t0 * 6 + n20) * 6 + jr];
        int n11 = map2[(t1 * 6 + n21) * 6 + jr];
        rp = prog + (size_t)tp * PPSTRIDE + rec_off(j3, jr);
        lp0 = lut1 + (t0 * 36 + n10) * 64;
        lp1 = lut1 + (t1 * 36 + n11) * 64;
        // 12 gather offsets: {t0 off, t1 off} per input variable
        if (lane < 12) {
            int half = lane & 1;               // 0 -> t0, 1 -> t1
            int jj   = lane >> 1;              // variable 0..5
            int node = half ? n11 : n10;
            int t    = half ? t1 : t0;
            int m    = map1[(t * 36 + node) * 6 + jj];
            int c    = m / 25;
            int r    = m - 25 * c;
            int kh   = r / 5;
            int kw   = r - 5 * kh;
            ((int*)rp)[lane] = c * HW_ + kh * W_ + kw;
        }
        rp += 48;
    }

    // Mobius transform along all 6 axes (stride 1 = LSB = x5).
    float c0 = lp0[lane];
    float c1 = lp1[lane];
#pragma unroll
    for (int s = 1; s < 64; s <<= 1) {
        float o0 = __shfl_xor(c0, s);
        float o1 = __shfl_xor(c1, s);
        if (lane & s) { c0 = c0 - o0; c1 = c1 - o1; }
    }
    f2* cp = (f2*)rp;
    f2 w; w.x = c0; w.y = c1;
    cp[lane] = w;
}

// ---- Fallback (ws too small): round-2 style direct evaluation ----
__device__ __forceinline__ float clamp01(float v) {
    return __builtin_amdgcn_fmed3f(v, 0.0f, 1.0f);
}

__device__ __forceinline__ float contract64s(const float* __restrict__ L,
                                             const float xs[6]) {
    float v[32];
#pragma unroll
    for (int a = 0; a < 32; ++a) {
        float b = L[2*a];
        v[a] = fmaf(xs[5], L[2*a+1] - b, b);
    }
#pragma unroll
    for (int a = 0; a < 16; ++a) v[a] = fmaf(xs[4], v[2*a+1] - v[2*a], v[2*a]);
#pragma unroll
    for (int a = 0; a < 8; ++a)  v[a] = fmaf(xs[3], v[2*a+1] - v[2*a], v[2*a]);
#pragma unroll
    for (int a = 0; a < 4; ++a)  v[a] = fmaf(xs[2], v[2*a+1] - v[2*a], v[2*a]);
#pragma unroll
    for (int a = 0; a < 2; ++a)  v[a] = fmaf(xs[1], v[2*a+1] - v[2*a], v[2*a]);
    return clamp01(fmaf(xs[0], v[1] - v[0], v[0]));
}

__global__ __launch_bounds__(BLOCK, 4)
void lutconv_fb(const float* __restrict__ x,
                const int* __restrict__ map1,
                const float* __restrict__ lut1,
                const int* __restrict__ map2,
                const float* __restrict__ lut2,
                const int* __restrict__ map3,
                const float* __restrict__ lut3,
                float* __restrict__ out) {
    const int g   = blockIdx.x % UBLOCKS * BLOCK + threadIdx.x;
    const int tg  = blockIdx.x / UBLOCKS;
    const int b   = g / NPOS;
    const int pos = g - b * NPOS;
    const int lin = (pos / OW_) * W_ + (pos - (pos / OW_) * OW_);
    const float* xb = x + (size_t)b * XSTRIDE;

#pragma unroll 1
    for (int tt = 0; tt < COUT / TGROUPS; ++tt) {
        const int t = tg * (COUT / TGROUPS) + tt;
        float h2[6];
#pragma unroll
        for (int j3 = 0; j3 < 6; ++j3) {
            int n2 = __builtin_amdgcn_readfirstlane(map3[t * 6 + j3]);
            float h1[6];
#pragma unroll
            for (int j1 = 0; j1 < 6; ++j1) {
                int n1 = __builtin_amdgcn_readfirstlane(map2[(t * 6 + n2) * 6 + j1]);
                float xs[6];
#pragma unroll
                for (int jj = 0; jj < 6; ++jj) {
                    int m = map1[(t * 36 + n1) * 6 + jj];
                    int c = m / 25, r = m - 25 * c, kh = r / 5, kw = r - 5 * kh;
                    int off = __builtin_amdgcn_readfirstlane(c * HW_ + kh * W_ + kw);
                    xs[jj] = xb[off + lin];
                }
                h1[j1] = contract64s(lut1 + (t * 36 + n1) * 64, xs);
            }
            h2[j3] = contract64s(lut2 + (t * 6 + n2) * 64, h1);
        }
        out[((size_t)b * COUT + t) * NPOS + pos] = contract64s(lut3 + t * 64, h2);
    }
}

extern "C" void kernel_launch(void* const* d_in, const int* in_sizes, int n_in,
                              void* d_out, int out_size, void* d_ws, size_t ws_size,
                              hipStream_t stream) {
    const float* x    = (const float*)d_in[0];
    const int*   map1 = (const int*)d_in[1];
    const float* lut1 = (const float*)d_in[2];
    const int*   map2 = (const int*)d_in[3];
    const float* lut2 = (const float*)d_in[4];
    const int*   map3 = (const int*)d_in[5];
    const float* lut3 = (const float*)d_in[6];
    float* out = (float*)d_out;

    if (ws_size >= (size_t)WS_NEEDED) {
        char* prog = (char*)d_ws;
        prep_prog<<<NTP * 43, 64, 0, stream>>>(map1, lut1, map2, lut2, map3, lut3, prog);
        lutconv_prog<<<UBLOCKS * TGROUPS, BLOCK, 0, stream>>>(x, prog, out);
    } else {
        lutconv_fb<<<UBLOCKS * TGROUPS, BLOCK, 0, stream>>>(
            x, map1, lut1, map2, lut2, map3, lut3, out);
    }
}

// Round 4
// 579.720 us; speedup vs baseline: 3.3910x; 3.3910x over previous
//
#include <hip/hip_runtime.h>

// Problem constants
#define B_      64
#define CIN     32
#define H_      28
#define W_      28
#define OH_     24
#define OW_     24
#define COUT    128
#define NPOS    (OH_ * OW_)          // 576
#define HW_     (H_ * W_)            // 784
#define XSTRIDE (CIN * HW_)          // 25088 floats per image
#define NPOSU   (B_ * NPOS)          // 36864
#define BHALF   32                   // pair partner: (b, b+32)

// Main-kernel mapping (position-pair units)
#define BLOCK    256
#define NPAIRU   (BHALF * NPOS)      // 18432
#define UBLOCKS  (NPAIRU / BLOCK)    // 72
#define NT       4                   // trees per block
#define TGROUPS  (COUT / NT)         // 32
#define NXCD     8
#define UPX      (UBLOCKS / NXCD)    // 9
// grid = UBLOCKS * TGROUPS = 2304

// Workspace: OFFS[COUT][36][6] ints (gather offsets, execution order),
//            COEF[COUT][43][64] floats (Mobius coefficients, execution order:
//            node n = j3*7+j1 for L1, j3*7+6 for L2, 42 for L3).
#define OFFS_INTS  (COUT * 36 * 6)           // 27648
#define COEF_FLTS  (COUT * 43 * 64)          // 352256
#define WS_NEEDED  ((OFFS_INTS + COEF_FLTS) * 4)

typedef float f2 __attribute__((ext_vector_type(2)));

// Guaranteed packed FMA: d = x*h + l on both 32-bit halves.
__device__ __forceinline__ f2 pkfma(f2 x, f2 h, f2 l) {
    f2 d;
    asm("v_pk_fma_f32 %0, %1, %2, %3" : "=v"(d) : "v"(x), "v"(h), "v"(l));
    return d;
}

__device__ __forceinline__ f2 clamp2(f2 v) {
    f2 r;
    r.x = __builtin_amdgcn_fmed3f(v.x, 0.0f, 1.0f);
    r.y = __builtin_amdgcn_fmed3f(v.y, 0.0f, 1.0f);
    return r;
}

// DFS Horner contraction over Mobius coefficients C[0..63] (uniform -> SGPR).
// Entry-pair a0 covers coeffs (2a0, 2a0+1), differing in the x5 (LSB) bit.
// Level M combines with xs[6-M]; leaf = C[2a0] + x5 * C[2a0+1].
template<int M>
struct RecM {
    static __device__ __forceinline__ f2 go(const float* __restrict__ C, int a0,
                                            const f2* xs) {
        f2 lo = RecM<M - 1>::go(C, a0, xs);
        f2 hi = RecM<M - 1>::go(C, a0 + (1 << (M - 2)), xs);
        return pkfma(xs[6 - M], hi, lo);
    }
};
template<>
struct RecM<1> {
    static __device__ __forceinline__ f2 go(const float* __restrict__ C, int a0,
                                            const f2* xs) {
        // lo/hi are wave-uniform (SGPR). 1-SGPR-per-VALU rule => compiler
        // emits ~1 mov + 2 v_fma (or op_sel-fused pk) per entry-pair.
        float lo = C[2 * a0];
        float hi = C[2 * a0 + 1];
        f2 r;
        r.x = fmaf(xs[5].x, hi, lo);
        r.y = fmaf(xs[5].y, hi, lo);
        return r;
    }
};

__device__ __forceinline__ f2 contract_m(const float* __restrict__ C, const f2* xs) {
    return clamp2(RecM<6>::go(C, 0, xs));
}

__global__ __launch_bounds__(BLOCK, 6)
void lutconv_m(const float* __restrict__ x,
               const int* __restrict__ OFFS,
               const float* __restrict__ COEF,
               float* __restrict__ out) {
    // XCD-locality decode: consecutive u-chunks pinned per XCD (tg fast).
    const int bid = blockIdx.x;
    const int xcd = bid % NXCD;
    const int j   = bid / NXCD;          // 0..287
    const int tg  = j % TGROUPS;         // 0..31
    const int us  = j / TGROUPS;         // 0..8
    const int u   = xcd * UPX + us;      // 0..71

    const int g   = u * BLOCK + threadIdx.x;   // 0..18431 (pair units)
    const int b   = g / NPOS;                  // 0..31 -> images (b, b+32)
    const int pos = g - b * NPOS;
    const int oh  = pos / OW_;
    const int ow  = pos - oh * OW_;
    const int lin = oh * W_ + ow;

    const float* xb0 = x + (size_t)b * XSTRIDE;
    const float* xb1 = xb0 + (size_t)BHALF * XSTRIDE;

#pragma unroll 1
    for (int tt = 0; tt < NT; ++tt) {
        const int t = tg * NT + tt;
        const float* Ct = COEF + (size_t)t * (43 * 64);
        const int*   Ot = OFFS + t * (36 * 6);

        f2 h2[6];
#pragma unroll
        for (int j3 = 0; j3 < 6; ++j3) {
            f2 h1[6];
#pragma unroll
            for (int j1 = 0; j1 < 6; ++j1) {
                const int* oi = Ot + (j3 * 6 + j1) * 6;
                f2 xs[6];
#pragma unroll
                for (int jj = 0; jj < 6; ++jj) {
                    int off = __builtin_amdgcn_readfirstlane(oi[jj]);
                    f2 w;
                    w.x = xb0[off + lin];
                    w.y = xb1[off + lin];
                    xs[jj] = w;
                }
                h1[j1] = contract_m(Ct + (j3 * 7 + j1) * 64, xs);
            }
            h2[j3] = contract_m(Ct + (j3 * 7 + 6) * 64, h1);
        }
        f2 r = contract_m(Ct + 42 * 64, h2);

        float* o0 = out + ((size_t)b * COUT + t) * NPOS + pos;
        o0[0] = r.x;
        o0[(size_t)BHALF * COUT * NPOS] = r.y;
    }
}

// ---- Program builder: one 64-thread block per (tree, node-record). ----
// Resolves map3/map2 indirection, precomputes gather offsets, Mobius-transforms
// each 64-entry LUT (6-stage shfl_xor butterfly — validated in round 3).
__global__ void prep(const int* __restrict__ map1, const float* __restrict__ lut1,
                     const int* __restrict__ map2, const float* __restrict__ lut2,
                     const int* __restrict__ map3, const float* __restrict__ lut3,
                     int* __restrict__ OFFS, float* __restrict__ COEF) {
    const int rec  = blockIdx.x % 43;
    const int t    = blockIdx.x / 43;
    const int lane = threadIdx.x;

    const float* lp;
    float* cp;
    if (rec == 42) {                        // L3 root
        lp = lut3 + t * 64;
        cp = COEF + ((size_t)t * 43 + 42) * 64;
    } else {
        const int j3 = rec / 7;
        const int jr = rec - 7 * j3;
        const int n2 = map3[t * 6 + j3];
        if (jr == 6) {                      // L2 node feeding root input j3
            lp = lut2 + (t * 6 + n2) * 64;
            cp = COEF + ((size_t)t * 43 + j3 * 7 + 6) * 64;
        } else {                            // L1 node: input jr of L2 node j3
            const int n1 = map2[(t * 6 + n2) * 6 + jr];
            lp = lut1 + (t * 36 + n1) * 64;
            cp = COEF + ((size_t)t * 43 + j3 * 7 + jr) * 64;
            if (lane < 6) {
                int m  = map1[(t * 36 + n1) * 6 + lane];
                int c  = m / 25;
                int r  = m - 25 * c;
                int kh = r / 5;
                int kw = r - 5 * kh;
                OFFS[t * 216 + (j3 * 6 + jr) * 6 + lane] = c * HW_ + kh * W_ + kw;
            }
        }
    }

    float cv = lp[lane];
#pragma unroll
    for (int s = 1; s < 64; s <<= 1) {
        float o = __shfl_xor(cv, s);
        if (lane & s) cv = cv - o;
    }
    cp[lane] = cv;
}

// ---- Fallback (ws too small): round-2/3 style direct evaluation ----
__device__ __forceinline__ float clamp01(float v) {
    return __builtin_amdgcn_fmed3f(v, 0.0f, 1.0f);
}

__device__ __forceinline__ float contract64s(const float* __restrict__ L,
                                             const float xs[6]) {
    float v[32];
#pragma unroll
    for (int a = 0; a < 32; ++a) {
        float b = L[2 * a];
        v[a] = fmaf(xs[5], L[2 * a + 1] - b, b);
    }
#pragma unroll
    for (int a = 0; a < 16; ++a) v[a] = fmaf(xs[4], v[2*a+1] - v[2*a], v[2*a]);
#pragma unroll
    for (int a = 0; a < 8; ++a)  v[a] = fmaf(xs[3], v[2*a+1] - v[2*a], v[2*a]);
#pragma unroll
    for (int a = 0; a < 4; ++a)  v[a] = fmaf(xs[2], v[2*a+1] - v[2*a], v[2*a]);
#pragma unroll
    for (int a = 0; a < 2; ++a)  v[a] = fmaf(xs[1], v[2*a+1] - v[2*a], v[2*a]);
    return clamp01(fmaf(xs[0], v[1] - v[0], v[0]));
}

__global__ __launch_bounds__(BLOCK, 4)
void lutconv_fb(const float* __restrict__ x,
                const int* __restrict__ map1, const float* __restrict__ lut1,
                const int* __restrict__ map2, const float* __restrict__ lut2,
                const int* __restrict__ map3, const float* __restrict__ lut3,
                float* __restrict__ out) {
    const int g   = (blockIdx.x % 144) * BLOCK + threadIdx.x;  // 0..36863
    const int tg  = blockIdx.x / 144;                          // 0..15
    const int b   = g / NPOS;
    const int pos = g - b * NPOS;
    const int lin = (pos / OW_) * W_ + (pos - (pos / OW_) * OW_);
    const float* xb = x + (size_t)b * XSTRIDE;

#pragma unroll 1
    for (int tt = 0; tt < 8; ++tt) {
        const int t = tg * 8 + tt;
        float h2[6];
#pragma unroll
        for (int j3 = 0; j3 < 6; ++j3) {
            int n2 = __builtin_amdgcn_readfirstlane(map3[t * 6 + j3]);
            float h1[6];
#pragma unroll
            for (int j1 = 0; j1 < 6; ++j1) {
                int n1 = __builtin_amdgcn_readfirstlane(map2[(t * 6 + n2) * 6 + j1]);
                float xs[6];
#pragma unroll
                for (int jj = 0; jj < 6; ++jj) {
                    int m = map1[(t * 36 + n1) * 6 + jj];
                    int c = m / 25, r = m - 25 * c, kh = r / 5, kw = r - 5 * kh;
                    int off = __builtin_amdgcn_readfirstlane(c * HW_ + kh * W_ + kw);
                    xs[jj] = xb[off + lin];
                }
                h1[j1] = contract64s(lut1 + (t * 36 + n1) * 64, xs);
            }
            h2[j3] = contract64s(lut2 + (t * 6 + n2) * 64, h1);
        }
        out[((size_t)b * COUT + t) * NPOS + pos] = contract64s(lut3 + t * 64, h2);
    }
}

extern "C" void kernel_launch(void* const* d_in, const int* in_sizes, int n_in,
                              void* d_out, int out_size, void* d_ws, size_t ws_size,
                              hipStream_t stream) {
    const float* x    = (const float*)d_in[0];
    const int*   map1 = (const int*)d_in[1];
    const float* lut1 = (const float*)d_in[2];
    const int*   map2 = (const int*)d_in[3];
    const float* lut2 = (const float*)d_in[4];
    const int*   map3 = (const int*)d_in[5];
    const float* lut3 = (const float*)d_in[6];
    float* out = (float*)d_out;

    if (ws_size >= (size_t)WS_NEEDED) {
        int*   OFFS = (int*)d_ws;
        float* COEF = (float*)((char*)d_ws + OFFS_INTS * 4);
        prep<<<COUT * 43, 64, 0, stream>>>(map1, lut1, map2, lut2, map3, lut3,
                                           OFFS, COEF);
        lutconv_m<<<UBLOCKS * TGROUPS, BLOCK, 0, stream>>>(x, OFFS, COEF, out);
    } else {
        lutconv_fb<<<144 * 16, BLOCK, 0, stream>>>(
            x, map1, lut1, map2, lut2, map3, lut3, out);
    }
}

// Round 5
// 529.276 us; speedup vs baseline: 3.7142x; 1.0953x over previous
//
#include <hip/hip_runtime.h>

// Problem constants
#define B_      64
#define CIN     32
#define H_      28
#define W_      28
#define OH_     24
#define OW_     24
#define COUT    128
#define NPOS    (OH_ * OW_)          // 576
#define HW_     (H_ * W_)            // 784
#define XSTRIDE (CIN * HW_)          // 25088 floats per image
#define BHALF   32                   // image partner: (b, b+32)

// Mapping: lane = (b0 in [0,32), pos); f2 halves = tree pair (2tp, 2tp+1).
// 4 outputs per lane per tree-pair.
#define BLOCK    256
#define NLANES   (BHALF * NPOS)      // 18432
#define UBLOCKS  (NLANES / BLOCK)    // 72
#define TPB      2                   // tree-pairs per block
#define NTP      64
#define TGROUPS  (NTP / TPB)         // 32
#define NXCD     8
#define UPX      (UBLOCKS / NXCD)    // 9
// grid = UBLOCKS * TGROUPS = 2304

// Per-tree-pair coefficient image: 43 nodes x 32 entry-pairs x f4
// {lo_t0, lo_t1, hi_t0, hi_t1} = 22016 B.
#define CF4_PER_TP (43 * 32)                 // 1376 f4
#define OFF_INTS   (NTP * 36 * 12)           // 27648 ints (byte offsets, x4)
#define COEF_FLTS  (NTP * 43 * 128)          // 352256 floats
#define WS_NEEDED  ((OFF_INTS + COEF_FLTS) * 4)   // 1519616

typedef float f2 __attribute__((ext_vector_type(2)));
typedef float f4 __attribute__((ext_vector_type(4)));
struct p2 { f2 a, b; };   // two image-units, each f2 over the tree pair

// Guaranteed packed FMA: d = x*h + l on both 32-bit halves.
__device__ __forceinline__ f2 pkfma(f2 x, f2 h, f2 l) {
    f2 d;
    asm("v_pk_fma_f32 %0, %1, %2, %3" : "=v"(d) : "v"(x), "v"(h), "v"(l));
    return d;
}

__device__ __forceinline__ f2 clamp2(f2 v) {
    f2 r;
    r.x = __builtin_amdgcn_fmed3f(v.x, 0.0f, 1.0f);
    r.y = __builtin_amdgcn_fmed3f(v.y, 0.0f, 1.0f);
    return r;
}

// DFS Horner contraction over LDS-resident Mobius coefficient records.
// Record a0 = {lo(f2 over trees), hi(f2)}: one ds_read_b128, two pkfma.
// Level M combines with xs[6-M]; pairs differ in the x5 (LSB) bit.
template<int M>
struct RecL {
    static __device__ __forceinline__ p2 go(const f4* __restrict__ C, int a0,
                                            const p2* xs) {
        p2 lo = RecL<M - 1>::go(C, a0, xs);
        p2 hi = RecL<M - 1>::go(C, a0 + (1 << (M - 2)), xs);
        p2 r;
        r.a = pkfma(xs[6 - M].a, hi.a, lo.a);
        r.b = pkfma(xs[6 - M].b, hi.b, lo.b);
        return r;
    }
};
template<>
struct RecL<1> {
    static __device__ __forceinline__ p2 go(const f4* __restrict__ C, int a0,
                                            const p2* xs) {
        f4 q = C[a0];                 // ds_read_b128, uniform addr -> broadcast
        f2 lo; lo.x = q.x; lo.y = q.y;
        f2 hi; hi.x = q.z; hi.y = q.w;
        p2 r;
        r.a = pkfma(xs[5].a, hi, lo);
        r.b = pkfma(xs[5].b, hi, lo);
        return r;
    }
};

__device__ __forceinline__ p2 contract2(const f4* __restrict__ C, const p2 xs[6]) {
    p2 r = RecL<6>::go(C, 0, xs);
    r.a = clamp2(r.a);
    r.b = clamp2(r.b);
    return r;
}

__global__ __launch_bounds__(BLOCK, 4)
void lutconv_l(const float* __restrict__ x,
               const int* __restrict__ OFFS,
               const f4* __restrict__ COEF,
               float* __restrict__ out) {
    __shared__ f4 CLs[CF4_PER_TP];

    // XCD-locality decode (r4-proven): chunk ranges pinned per XCD.
    const int bid = blockIdx.x;
    const int xcd = bid % NXCD;
    const int j   = bid / NXCD;          // 0..287
    const int tg  = j % TGROUPS;         // 0..31
    const int us  = j / TGROUPS;         // 0..8
    const int u   = xcd * UPX + us;      // 0..71

    const int g   = u * BLOCK + threadIdx.x;   // 0..18431
    const int b0  = g / NPOS;                  // 0..31 -> images (b0, b0+32)
    const int pos = g - b0 * NPOS;
    const int oh  = pos / OW_;
    const int ow  = pos - oh * OW_;
    const unsigned lin   = oh * W_ + ow;
    const unsigned voff0 = (b0 * XSTRIDE + lin) * 4u;          // byte voffset
    const unsigned voff1 = voff0 + BHALF * XSTRIDE * 4u;
    const char* xc = (const char*)x;

#pragma unroll 1
    for (int tpi = 0; tpi < TPB; ++tpi) {
        const int tp = tg * TPB + tpi;

        if (tpi) __syncthreads();            // drain readers before restage
        {
            const f4* src = COEF + (size_t)tp * CF4_PER_TP;
#pragma unroll
            for (int k = 0; k < 6; ++k) {
                int i = k * BLOCK + threadIdx.x;
                if (i < CF4_PER_TP) CLs[i] = src[i];
            }
        }
        __syncthreads();

        const int* Ot = OFFS + tp * (36 * 12);

        p2 h2[6];
#pragma unroll
        for (int j3 = 0; j3 < 6; ++j3) {
            p2 h1[6];
#pragma unroll
            for (int j1 = 0; j1 < 6; ++j1) {
                const int* oi = Ot + (j3 * 6 + j1) * 12;
                p2 xs[6];
#pragma unroll
                for (int jj = 0; jj < 6; ++jj) {
                    int o0 = __builtin_amdgcn_readfirstlane(oi[2 * jj]);
                    int o1 = __builtin_amdgcn_readfirstlane(oi[2 * jj + 1]);
                    f2 va, vb;
                    va.x = *(const float*)(xc + o0 + voff0);
                    va.y = *(const float*)(xc + o1 + voff0);
                    vb.x = *(const float*)(xc + o0 + voff1);
                    vb.y = *(const float*)(xc + o1 + voff1);
                    xs[jj].a = va;
                    xs[jj].b = vb;
                }
                h1[j1] = contract2(&CLs[(j3 * 7 + j1) * 32], xs);
            }
            h2[j3] = contract2(&CLs[(j3 * 7 + 6) * 32], h1);
        }
        p2 r = contract2(&CLs[42 * 32], h2);

        size_t ob = ((size_t)b0 * COUT + 2 * tp) * NPOS + pos;
        out[ob]        = r.a.x;
        out[ob + NPOS] = r.a.y;
        size_t ob2 = ob + (size_t)BHALF * COUT * NPOS;
        out[ob2]        = r.b.x;
        out[ob2 + NPOS] = r.b.y;
    }
}

// ---- Program builder: one 64-thread block per (tree-pair, node). ----
// Resolves map3/map2, precomputes byte gather offsets, Mobius-transforms each
// 64-entry LUT (shfl_xor butterfly, r3/r4-proven), stores tree-pair-interleaved
// {lo_t0, lo_t1, hi_t0, hi_t1} records in execution order.
__global__ void prep(const int* __restrict__ map1, const float* __restrict__ lut1,
                     const int* __restrict__ map2, const float* __restrict__ lut2,
                     const int* __restrict__ map3, const float* __restrict__ lut3,
                     int* __restrict__ OFFS, float* __restrict__ COEF) {
    const int rec  = blockIdx.x % 43;
    const int tp   = blockIdx.x / 43;
    const int lane = threadIdx.x;
    const int t0 = 2 * tp, t1 = 2 * tp + 1;

    const float* lp0;
    const float* lp1;
    int node;
    if (rec == 42) {                        // L3 root
        node = 42;
        lp0 = lut3 + t0 * 64;
        lp1 = lut3 + t1 * 64;
    } else {
        const int j3 = rec / 7;
        const int jr = rec - 7 * j3;
        const int n20 = map3[t0 * 6 + j3];
        const int n21 = map3[t1 * 6 + j3];
        if (jr == 6) {                      // L2 node feeding root input j3
            node = j3 * 7 + 6;
            lp0 = lut2 + (t0 * 6 + n20) * 64;
            lp1 = lut2 + (t1 * 6 + n21) * 64;
        } else {                            // L1 node: input jr of L2 node j3
            const int n10 = map2[(t0 * 6 + n20) * 6 + jr];
            const int n11 = map2[(t1 * 6 + n21) * 6 + jr];
            node = j3 * 7 + jr;
            lp0 = lut1 + (t0 * 36 + n10) * 64;
            lp1 = lut1 + (t1 * 36 + n11) * 64;
            if (lane < 12) {
                int h  = lane & 1;                 // 0 -> t0, 1 -> t1
                int jj = lane >> 1;                // variable 0..5
                int n1 = h ? n11 : n10;
                int t  = h ? t1 : t0;
                int m  = map1[(t * 36 + n1) * 6 + jj];
                int c  = m / 25;
                int r  = m - 25 * c;
                int kh = r / 5;
                int kw = r - 5 * kh;
                OFFS[(tp * 36 + j3 * 6 + jr) * 12 + jj * 2 + h] =
                    (c * HW_ + kh * W_ + kw) * 4;  // byte offset
            }
        }
    }

    float c0 = lp0[lane];
    float c1 = lp1[lane];
#pragma unroll
    for (int s = 1; s < 64; s <<= 1) {
        float o0 = __shfl_xor(c0, s);
        float o1 = __shfl_xor(c1, s);
        if (lane & s) { c0 -= o0; c1 -= o1; }
    }
    // Record layout: pair p = lane>>1; slot = (lane&1)*2 + tree.
    float* cp = COEF + ((size_t)tp * 43 + node) * 128;
    int slot = (lane >> 1) * 4 + (lane & 1) * 2;
    cp[slot]     = c0;
    cp[slot + 1] = c1;
}

// ---- Fallback (ws too small): r4-proven direct evaluation ----
__device__ __forceinline__ float clamp01(float v) {
    return __builtin_amdgcn_fmed3f(v, 0.0f, 1.0f);
}

__device__ __forceinline__ float contract64s(const float* __restrict__ L,
                                             const float xs[6]) {
    float v[32];
#pragma unroll
    for (int a = 0; a < 32; ++a) {
        float b = L[2 * a];
        v[a] = fmaf(xs[5], L[2 * a + 1] - b, b);
    }
#pragma unroll
    for (int a = 0; a < 16; ++a) v[a] = fmaf(xs[4], v[2*a+1] - v[2*a], v[2*a]);
#pragma unroll
    for (int a = 0; a < 8; ++a)  v[a] = fmaf(xs[3], v[2*a+1] - v[2*a], v[2*a]);
#pragma unroll
    for (int a = 0; a < 4; ++a)  v[a] = fmaf(xs[2], v[2*a+1] - v[2*a], v[2*a]);
#pragma unroll
    for (int a = 0; a < 2; ++a)  v[a] = fmaf(xs[1], v[2*a+1] - v[2*a], v[2*a]);
    return clamp01(fmaf(xs[0], v[1] - v[0], v[0]));
}

__global__ __launch_bounds__(BLOCK, 4)
void lutconv_fb(const float* __restrict__ x,
                const int* __restrict__ map1, const float* __restrict__ lut1,
                const int* __restrict__ map2, const float* __restrict__ lut2,
                const int* __restrict__ map3, const float* __restrict__ lut3,
                float* __restrict__ out) {
    const int g   = (blockIdx.x % 144) * BLOCK + threadIdx.x;
    const int tg  = blockIdx.x / 144;
    const int b   = g / NPOS;
    const int pos = g - b * NPOS;
    const int lin = (pos / OW_) * W_ + (pos - (pos / OW_) * OW_);
    const float* xb = x + (size_t)b * XSTRIDE;

#pragma unroll 1
    for (int tt = 0; tt < 8; ++tt) {
        const int t = tg * 8 + tt;
        float h2[6];
#pragma unroll
        for (int j3 = 0; j3 < 6; ++j3) {
            int n2 = __builtin_amdgcn_readfirstlane(map3[t * 6 + j3]);
            float h1[6];
#pragma unroll
            for (int j1 = 0; j1 < 6; ++j1) {
                int n1 = __builtin_amdgcn_readfirstlane(map2[(t * 6 + n2) * 6 + j1]);
                float xs[6];
#pragma unroll
                for (int jj = 0; jj < 6; ++jj) {
                    int m = map1[(t * 36 + n1) * 6 + jj];
                    int c = m / 25, r = m - 25 * c, kh = r / 5, kw = r - 5 * kh;
                    int off = __builtin_amdgcn_readfirstlane(c * HW_ + kh * W_ + kw);
                    xs[jj] = xb[off + lin];
                }
                h1[j1] = contract64s(lut1 + (t * 36 + n1) * 64, xs);
            }
            h2[j3] = contract64s(lut2 + (t * 6 + n2) * 64, h1);
        }
        out[((size_t)b * COUT + t) * NPOS + pos] = contract64s(lut3 + t * 64, h2);
    }
}

extern "C" void kernel_launch(void* const* d_in, const int* in_sizes, int n_in,
                              void* d_out, int out_size, void* d_ws, size_t ws_size,
                              hipStream_t stream) {
    const float* x    = (const float*)d_in[0];
    const int*   map1 = (const int*)d_in[1];
    const float* lut1 = (const float*)d_in[2];
    const int*   map2 = (const int*)d_in[3];
    const float* lut2 = (const float*)d_in[4];
    const int*   map3 = (const int*)d_in[5];
    const float* lut3 = (const float*)d_in[6];
    float* out = (float*)d_out;

    if (ws_size >= (size_t)WS_NEEDED) {
        int*   OFFS = (int*)d_ws;
        float* COEF = (float*)((char*)d_ws + OFF_INTS * 4);
        prep<<<NTP * 43, 64, 0, stream>>>(map1, lut1, map2, lut2, map3, lut3,
                                          OFFS, COEF);
        lutconv_l<<<UBLOCKS * TGROUPS, BLOCK, 0, stream>>>(
            x, OFFS, (const f4*)COEF, out);
    } else {
        lutconv_fb<<<144 * 16, BLOCK, 0, stream>>>(
            x, map1, lut1, map2, lut2, map3, lut3, out);
    }
}

// Round 6
// 433.363 us; speedup vs baseline: 4.5363x; 1.2213x over previous
//
#include <hip/hip_runtime.h>

// Problem constants
#define B_      64
#define CIN     32
#define H_      28
#define W_      28
#define OH_     24
#define OW_     24
#define COUT    128
#define NPOS    (OH_ * OW_)          // 576
#define HW_     (H_ * W_)            // 784
#define XSTRIDE (CIN * HW_)          // 25088 floats per image
#define BHALF   32                   // image partner: (b, b+32)

// Mapping: lane = (b0 in [0,32), pos); f2 halves = tree pair (2tp, 2tp+1).
// 4 outputs per lane per tree-pair (2 images x 2 trees).
#define BLOCK    256
#define NLANES   (BHALF * NPOS)      // 18432
#define UBLOCKS  (NLANES / BLOCK)    // 72
#define TPB      2                   // tree-pairs per block
#define NTP      64
#define TGROUPS  (NTP / TPB)         // 32
#define NXCD     8
#define UPX      (UBLOCKS / NXCD)    // 9
// grid = UBLOCKS * TGROUPS = 2304

// Per-tree-pair coefficient image: 43 nodes x 32 entry-pairs x f4
// {lo_t0, lo_t1, hi_t0, hi_t1} = 22016 B.
#define CF4_PER_TP (43 * 32)                 // 1376 f4
#define OFF_INTS   (NTP * 36 * 12)           // 27648 ints (byte offsets)
#define COEF_FLTS  (NTP * 43 * 128)          // 352256 floats
#define WS_NEEDED  ((OFF_INTS + COEF_FLTS) * 4)   // 1519616

typedef float f2 __attribute__((ext_vector_type(2)));
typedef float f4 __attribute__((ext_vector_type(4)));
struct p2 { f2 a, b; };   // two image-units, each f2 over the tree pair

// Packed FMA d = x*h + l. __builtin_elementwise_fma on <2 x float> selects
// v_pk_fma_f32 on gfx90a+ while leaving regalloc full freedom (the round-5
// inline-asm version pinned ~100 live aligned pairs -> scratch spills,
// seen as 125 MB WRITE_SIZE).
__device__ __forceinline__ f2 pkfma(f2 x, f2 h, f2 l) {
    return __builtin_elementwise_fma(x, h, l);
}

__device__ __forceinline__ f2 clamp2(f2 v) {
    f2 r;
    r.x = __builtin_amdgcn_fmed3f(v.x, 0.0f, 1.0f);
    r.y = __builtin_amdgcn_fmed3f(v.y, 0.0f, 1.0f);
    return r;
}

// DFS Horner contraction over LDS-resident Mobius coefficient records.
// Record a0 = {lo(f2 over trees), hi(f2)}: one ds_read_b128 (uniform addr ->
// broadcast, conflict-free), four pkfma. Level M combines with xs[6-M].
template<int M>
struct RecL {
    static __device__ __forceinline__ p2 go(const f4* __restrict__ C, int a0,
                                            const p2* xs) {
        p2 lo = RecL<M - 1>::go(C, a0, xs);
        p2 hi = RecL<M - 1>::go(C, a0 + (1 << (M - 2)), xs);
        p2 r;
        r.a = pkfma(xs[6 - M].a, hi.a, lo.a);
        r.b = pkfma(xs[6 - M].b, hi.b, lo.b);
        return r;
    }
};
template<>
struct RecL<1> {
    static __device__ __forceinline__ p2 go(const f4* __restrict__ C, int a0,
                                            const p2* xs) {
        f4 q = C[a0];                 // ds_read_b128 broadcast
        f2 lo; lo.x = q.x; lo.y = q.y;
        f2 hi; hi.x = q.z; hi.y = q.w;   // aligned {z,w} sub-pair: no shuffle
        p2 r;
        r.a = pkfma(xs[5].a, hi, lo);
        r.b = pkfma(xs[5].b, hi, lo);
        return r;
    }
};

__device__ __forceinline__ p2 contract2(const f4* __restrict__ C, const p2 xs[6]) {
    p2 r = RecL<6>::go(C, 0, xs);
    r.a = clamp2(r.a);
    r.b = clamp2(r.b);
    return r;
}

__global__ __launch_bounds__(BLOCK, 3)   // VGPR cap ~168: room for ~110 live, no spill
void lutconv_l(const float* __restrict__ x,
               const int* __restrict__ OFFS,
               const f4* __restrict__ COEF,
               float* __restrict__ out) {
    __shared__ f4 CLs[CF4_PER_TP];

    // XCD-locality decode (r4-proven): chunk ranges pinned per XCD.
    const int bid = blockIdx.x;
    const int xcd = bid % NXCD;
    const int j   = bid / NXCD;          // 0..287
    const int tg  = j % TGROUPS;         // 0..31
    const int us  = j / TGROUPS;         // 0..8
    const int u   = xcd * UPX + us;      // 0..71

    const int g   = u * BLOCK + threadIdx.x;   // 0..18431
    const int b0  = g / NPOS;                  // 0..31 -> images (b0, b0+32)
    const int pos = g - b0 * NPOS;
    const int oh  = pos / OW_;
    const int ow  = pos - oh * OW_;
    const unsigned lin   = oh * W_ + ow;
    const unsigned voff0 = (b0 * XSTRIDE + lin) * 4u;          // byte voffset
    const unsigned voff1 = voff0 + BHALF * XSTRIDE * 4u;
    const char* xc = (const char*)x;

#pragma unroll 1
    for (int tpi = 0; tpi < TPB; ++tpi) {
        const int tp = tg * TPB + tpi;

        if (tpi) __syncthreads();            // drain readers before restage
        {
            const f4* src = COEF + (size_t)tp * CF4_PER_TP;
#pragma unroll
            for (int k = 0; k < 6; ++k) {
                int i = k * BLOCK + threadIdx.x;
                if (i < CF4_PER_TP) CLs[i] = src[i];
            }
        }
        __syncthreads();

        const int* Ot = OFFS + tp * (36 * 12);

        p2 h2[6];
#pragma unroll
        for (int j3 = 0; j3 < 6; ++j3) {
            p2 h1[6];
#pragma unroll
            for (int j1 = 0; j1 < 6; ++j1) {
                const int* oi = Ot + (j3 * 6 + j1) * 12;
                p2 xs[6];
#pragma unroll
                for (int jj = 0; jj < 6; ++jj) {
                    int o0 = __builtin_amdgcn_readfirstlane(oi[2 * jj]);
                    int o1 = __builtin_amdgcn_readfirstlane(oi[2 * jj + 1]);
                    f2 va, vb;
                    va.x = *(const float*)(xc + o0 + voff0);
                    va.y = *(const float*)(xc + o1 + voff0);
                    vb.x = *(const float*)(xc + o0 + voff1);
                    vb.y = *(const float*)(xc + o1 + voff1);
                    xs[jj].a = va;
                    xs[jj].b = vb;
                }
                h1[j1] = contract2(&CLs[(j3 * 7 + j1) * 32], xs);
            }
            h2[j3] = contract2(&CLs[(j3 * 7 + 6) * 32], h1);
        }
        p2 r = contract2(&CLs[42 * 32], h2);

        size_t ob = ((size_t)b0 * COUT + 2 * tp) * NPOS + pos;
        out[ob]        = r.a.x;
        out[ob + NPOS] = r.a.y;
        size_t ob2 = ob + (size_t)BHALF * COUT * NPOS;
        out[ob2]        = r.b.x;
        out[ob2 + NPOS] = r.b.y;
    }
}

// ---- Program builder: one 64-thread block per (tree-pair, node). ----
// Resolves map3/map2, precomputes byte gather offsets, Mobius-transforms each
// 64-entry LUT (shfl_xor butterfly, r3/r4-proven), stores tree-pair-interleaved
// {lo_t0, lo_t1, hi_t0, hi_t1} records in execution order.
__global__ void prep(const int* __restrict__ map1, const float* __restrict__ lut1,
                     const int* __restrict__ map2, const float* __restrict__ lut2,
                     const int* __restrict__ map3, const float* __restrict__ lut3,
                     int* __restrict__ OFFS, float* __restrict__ COEF) {
    const int rec  = blockIdx.x % 43;
    const int tp   = blockIdx.x / 43;
    const int lane = threadIdx.x;
    const int t0 = 2 * tp, t1 = 2 * tp + 1;

    const float* lp0;
    const float* lp1;
    int node;
    if (rec == 42) {                        // L3 root
        node = 42;
        lp0 = lut3 + t0 * 64;
        lp1 = lut3 + t1 * 64;
    } else {
        const int j3 = rec / 7;
        const int jr = rec - 7 * j3;
        const int n20 = map3[t0 * 6 + j3];
        const int n21 = map3[t1 * 6 + j3];
        if (jr == 6) {                      // L2 node feeding root input j3
            node = j3 * 7 + 6;
            lp0 = lut2 + (t0 * 6 + n20) * 64;
            lp1 = lut2 + (t1 * 6 + n21) * 64;
        } else {                            // L1 node: input jr of L2 node j3
            const int n10 = map2[(t0 * 6 + n20) * 6 + jr];
            const int n11 = map2[(t1 * 6 + n21) * 6 + jr];
            node = j3 * 7 + jr;
            lp0 = lut1 + (t0 * 36 + n10) * 64;
            lp1 = lut1 + (t1 * 36 + n11) * 64;
            if (lane < 12) {
                int h  = lane & 1;                 // 0 -> t0, 1 -> t1
                int jj = lane >> 1;                // variable 0..5
                int n1 = h ? n11 : n10;
                int t  = h ? t1 : t0;
                int m  = map1[(t * 36 + n1) * 6 + jj];
                int c  = m / 25;
                int r  = m - 25 * c;
                int kh = r / 5;
                int kw = r - 5 * kh;
                OFFS[(tp * 36 + j3 * 6 + jr) * 12 + jj * 2 + h] =
                    (c * HW_ + kh * W_ + kw) * 4;  // byte offset
            }
        }
    }

    float c0 = lp0[lane];
    float c1 = lp1[lane];
#pragma unroll
    for (int s = 1; s < 64; s <<= 1) {
        float o0 = __shfl_xor(c0, s);
        float o1 = __shfl_xor(c1, s);
        if (lane & s) { c0 -= o0; c1 -= o1; }
    }
    // Record layout: pair p = lane>>1; slot = (lane&1)*2 + tree.
    float* cp = COEF + ((size_t)tp * 43 + node) * 128;
    int slot = (lane >> 1) * 4 + (lane & 1) * 2;
    cp[slot]     = c0;
    cp[slot + 1] = c1;
}

// ---- Fallback (ws too small): r4-proven direct evaluation ----
__device__ __forceinline__ float clamp01(float v) {
    return __builtin_amdgcn_fmed3f(v, 0.0f, 1.0f);
}

__device__ __forceinline__ float contract64s(const float* __restrict__ L,
                                             const float xs[6]) {
    float v[32];
#pragma unroll
    for (int a = 0; a < 32; ++a) {
        float b = L[2 * a];
        v[a] = fmaf(xs[5], L[2 * a + 1] - b, b);
    }
#pragma unroll
    for (int a = 0; a < 16; ++a) v[a] = fmaf(xs[4], v[2*a+1] - v[2*a], v[2*a]);
#pragma unroll
    for (int a = 0; a < 8; ++a)  v[a] = fmaf(xs[3], v[2*a+1] - v[2*a], v[2*a]);
#pragma unroll
    for (int a = 0; a < 4; ++a)  v[a] = fmaf(xs[2], v[2*a+1] - v[2*a], v[2*a]);
#pragma unroll
    for (int a = 0; a < 2; ++a)  v[a] = fmaf(xs[1], v[2*a+1] - v[2*a], v[2*a]);
    return clamp01(fmaf(xs[0], v[1] - v[0], v[0]));
}

__global__ __launch_bounds__(BLOCK, 4)
void lutconv_fb(const float* __restrict__ x,
                const int* __restrict__ map1, const float* __restrict__ lut1,
                const int* __restrict__ map2, const float* __restrict__ lut2,
                const int* __restrict__ map3, const float* __restrict__ lut3,
                float* __restrict__ out) {
    const int g   = (blockIdx.x % 144) * BLOCK + threadIdx.x;
    const int tg  = blockIdx.x / 144;
    const int b   = g / NPOS;
    const int pos = g - b * NPOS;
    const int lin = (pos / OW_) * W_ + (pos - (pos / OW_) * OW_);
    const float* xb = x + (size_t)b * XSTRIDE;

#pragma unroll 1
    for (int tt = 0; tt < 8; ++tt) {
        const int t = tg * 8 + tt;
        float h2[6];
#pragma unroll
        for (int j3 = 0; j3 < 6; ++j3) {
            int n2 = __builtin_amdgcn_readfirstlane(map3[t * 6 + j3]);
            float h1[6];
#pragma unroll
            for (int j1 = 0; j1 < 6; ++j1) {
                int n1 = __builtin_amdgcn_readfirstlane(map2[(t * 6 + n2) * 6 + j1]);
                float xs[6];
#pragma unroll
                for (int jj = 0; jj < 6; ++jj) {
                    int m = map1[(t * 36 + n1) * 6 + jj];
                    int c = m / 25, r = m - 25 * c, kh = r / 5, kw = r - 5 * kh;
                    int off = __builtin_amdgcn_readfirstlane(c * HW_ + kh * W_ + kw);
                    xs[jj] = xb[off + lin];
                }
                h1[j1] = contract64s(lut1 + (t * 36 + n1) * 64, xs);
            }
            h2[j3] = contract64s(lut2 + (t * 6 + n2) * 64, h1);
        }
        out[((size_t)b * COUT + t) * NPOS + pos] = contract64s(lut3 + t * 64, h2);
    }
}

extern "C" void kernel_launch(void* const* d_in, const int* in_sizes, int n_in,
                              void* d_out, int out_size, void* d_ws, size_t ws_size,
                              hipStream_t stream) {
    const float* x    = (const float*)d_in[0];
    const int*   map1 = (const int*)d_in[1];
    const float* lut1 = (const float*)d_in[2];
    const int*   map2 = (const int*)d_in[3];
    const float* lut2 = (const float*)d_in[4];
    const int*   map3 = (const int*)d_in[5];
    const float* lut3 = (const float*)d_in[6];
    float* out = (float*)d_out;

    if (ws_size >= (size_t)WS_NEEDED) {
        int*   OFFS = (int*)d_ws;
        float* COEF = (float*)((char*)d_ws + OFF_INTS * 4);
        prep<<<NTP * 43, 64, 0, stream>>>(map1, lut1, map2, lut2, map3, lut3,
                                          OFFS, COEF);
        lutconv_l<<<UBLOCKS * TGROUPS, BLOCK, 0, stream>>>(
            x, OFFS, (const f4*)COEF, out);
    } else {
        lutconv_fb<<<144 * 16, BLOCK, 0, stream>>>(
            x, map1, lut1, map2, lut2, map3, lut3, out);
    }
}